// Round 1
// baseline (1364.284 us; speedup 1.0000x reference)
//
#include <hip/hip_runtime.h>

#define NN 50000
#define EE 800000

// ---------- helpers ----------
__device__ __forceinline__ float bf_lo(unsigned u){ return __uint_as_float(u << 16); }
__device__ __forceinline__ float bf_hi(unsigned u){ return __uint_as_float(u & 0xffff0000u); }
__device__ __forceinline__ unsigned short f2bf(float f){
  unsigned x = __float_as_uint(f);
  x += 0x7fffu + ((x >> 16) & 1u);       // RNE
  return (unsigned short)(x >> 16);
}
__device__ __forceinline__ float gelu_exact(float x){
  return x * 0.5f * (1.0f + erff(x * 0.70710678118654752f));
}
__device__ __forceinline__ void atomic_add_f32(float* p, float v){
  __hip_atomic_fetch_add(p, v, __ATOMIC_RELAXED, __HIP_MEMORY_SCOPE_AGENT);
}

// ---------- kernel 1: LN + QKV (bf16 out) + seq-normalize (bf16 out) ----------
#define NB 48
__global__ __launch_bounds__(384) void node_pre(
    const float* __restrict__ x, const float* __restrict__ seq,
    const float* __restrict__ ln_g, const float* __restrict__ ln_b,
    const float* __restrict__ Wq, const float* __restrict__ bq,
    const float* __restrict__ Wk, const float* __restrict__ bk,
    const float* __restrict__ Wv, const float* __restrict__ bv,
    unsigned short* __restrict__ qb, unsigned short* __restrict__ kb,
    unsigned short* __restrict__ vb, unsigned short* __restrict__ snb)
{
  __shared__ float h_lds[NB][132];   // +4 pad: breaks bank aliasing on LN writes
  const int t = threadIdx.x;
  const int nbase = blockIdx.x * NB;

  // --- LayerNorm: 8 threads per row, 16 elems each ---
  {
    const int row = t >> 3, sub = t & 7;
    const int n = nbase + row;
    if (n < NN) {
      const float* xp = x + (size_t)n * 128 + sub * 16;
      float vals[16];
      float s = 0.f, ss = 0.f;
      #pragma unroll
      for (int j = 0; j < 16; j += 4) {
        float4 v4 = *(const float4*)(xp + j);
        vals[j] = v4.x; vals[j+1] = v4.y; vals[j+2] = v4.z; vals[j+3] = v4.w;
        s += v4.x + v4.y + v4.z + v4.w;
        ss += v4.x*v4.x + v4.y*v4.y + v4.z*v4.z + v4.w*v4.w;
      }
      #pragma unroll
      for (int o = 1; o < 8; o <<= 1) { s += __shfl_xor(s, o); ss += __shfl_xor(ss, o); }
      float mu = s * (1.f / 128.f);
      float var = ss * (1.f / 128.f) - mu * mu;
      float rs = rsqrtf(var + 1e-5f);
      #pragma unroll
      for (int j = 0; j < 16; j++) {
        int c = sub * 16 + j;
        h_lds[row][c] = (vals[j] - mu) * rs * ln_g[c] + ln_b[c];
      }
      // --- seq normalize: same 8 threads, 8 elems each ---
      const float* sp = seq + (size_t)n * 64 + sub * 8;
      float4 a = *(const float4*)(sp);
      float4 b4 = *(const float4*)(sp + 4);
      float q2 = a.x*a.x + a.y*a.y + a.z*a.z + a.w*a.w
               + b4.x*b4.x + b4.y*b4.y + b4.z*b4.z + b4.w*b4.w;
      #pragma unroll
      for (int o = 1; o < 8; o <<= 1) q2 += __shfl_xor(q2, o);
      float inv = 1.0f / fmaxf(sqrtf(q2), 1e-12f);
      unsigned short* op = snb + (size_t)n * 64 + sub * 8;
      op[0]=f2bf(a.x*inv);  op[1]=f2bf(a.y*inv);  op[2]=f2bf(a.z*inv);  op[3]=f2bf(a.w*inv);
      op[4]=f2bf(b4.x*inv); op[5]=f2bf(b4.y*inv); op[6]=f2bf(b4.z*inv); op[7]=f2bf(b4.w*inv);
    }
  }
  __syncthreads();

  // --- QKV: thread t owns output column t (0..127 q, 128..255 k, 256..383 v) ---
  const int mat = t >> 7;          // wave-uniform (2 waves per matrix)
  const int r = t & 127;
  const float* W = (mat == 0) ? Wq : (mat == 1) ? Wk : Wv;
  const float* B = (mat == 0) ? bq : (mat == 1) ? bk : bv;
  unsigned short* O = (mat == 0) ? qb : (mat == 1) ? kb : vb;

  float acc[NB];
  #pragma unroll
  for (int n = 0; n < NB; n++) acc[n] = 0.f;

  for (int i = 0; i < 128; i += 4) {
    float4 w4 = *(const float4*)(W + (size_t)r * 128 + i);
    #pragma unroll
    for (int n = 0; n < NB; n++) {
      float4 h4 = *(const float4*)(&h_lds[n][i]);   // broadcast read
      acc[n] += w4.x*h4.x + w4.y*h4.y + w4.z*h4.z + w4.w*h4.w;
    }
  }
  float bias = B[r];
  #pragma unroll
  for (int n = 0; n < NB; n++) {
    int ng = nbase + n;
    if (ng < NN) O[(size_t)ng * 128 + r] = f2bf(acc[n] + bias);
  }
}

// ---------- kernel 2: per-edge logits + exp + atomic accumulate ----------
__global__ __launch_bounds__(256) void edge_k(
    const int* __restrict__ ei, const float* __restrict__ edge_attr,
    const unsigned short* __restrict__ qb, const unsigned short* __restrict__ kb,
    const unsigned short* __restrict__ vb, const unsigned short* __restrict__ snb,
    const float* __restrict__ We0a, const float* __restrict__ be0a,
    const float* __restrict__ We0b, const float* __restrict__ be0b,
    const float* __restrict__ We1a, const float* __restrict__ be1a,
    const float* __restrict__ We1b, const float* __restrict__ be1b,
    const float* __restrict__ Ws1, const float* __restrict__ bs1,
    const float* __restrict__ Ws2, const float* __restrict__ bs2,
    float* __restrict__ num, float* __restrict__ den)
{
  __shared__ float sWs1[128 * 64];   // [j][i] row-major (as source)
  __shared__ float sWs2T[128 * 8];   // [j][o]
  __shared__ float sWea[2 * 32 * 16];
  __shared__ float sWebT[2 * 32 * 8];
  __shared__ float sbea[2 * 32];
  __shared__ float sbeb[2 * 8];
  __shared__ float sbs1[128];
  __shared__ float sbs2[8];
  __shared__ float sEx[4 * 64 * 9];  // [wave][edge_lane][head] pad 9

  const int t = threadIdx.x;
  for (int idx = t; idx < 8192; idx += 256) sWs1[idx] = Ws1[idx];
  for (int idx = t; idx < 1024; idx += 256) { int j = idx >> 3, o = idx & 7; sWs2T[idx] = Ws2[o * 128 + j]; }
  for (int idx = t; idx < 1024; idx += 256) sWea[idx] = (idx < 512) ? We0a[idx] : We1a[idx - 512];
  for (int idx = t; idx < 512;  idx += 256) { int e2 = idx >> 8, rem = idx & 255, j = rem >> 3, o = rem & 7;
                                              sWebT[idx] = (e2 ? We1b : We0b)[o * 32 + j]; }
  if (t < 64)  sbea[t] = (t < 32) ? be0a[t] : be1a[t - 32];
  if (t < 16)  sbeb[t] = (t < 8) ? be0b[t] : be1b[t - 8];
  if (t < 128) sbs1[t] = bs1[t];
  if (t < 8)   sbs2[t] = bs2[t];
  __syncthreads();

  const int e = blockIdx.x * 256 + t;    // grid sized exactly: e < EE always
  const int lane = t & 63, wid = t >> 6;
  const int src = ei[e];
  const int dst = ei[EE + e];

  // ---- edge-type MLP (lane-per-edge) ----
  float ef[16], a16, a17;
  {
    const float2* p2 = (const float2*)(edge_attr + (size_t)e * 18);
    float2 p[9];
    #pragma unroll
    for (int i = 0; i < 9; i++) p[i] = p2[i];
    #pragma unroll
    for (int i = 0; i < 8; i++) { ef[2*i] = p[i].x; ef[2*i+1] = p[i].y; }
    a16 = p[8].x; a17 = p[8].y;
  }
  const int sel = (a17 > a16) ? 1 : 0;   // argmax (tie -> 0)
  const float* Wa = sWea + sel * 512;
  const float* Wb = sWebT + sel * 256;
  const float* ba = sbea + sel * 32;
  const float* bb = sbeb + sel * 8;
  float m[8];
  #pragma unroll
  for (int o = 0; o < 8; o++) m[o] = bb[o];
  for (int j = 0; j < 32; j++) {
    float hs = ba[j];
    #pragma unroll
    for (int i = 0; i < 16; i++) hs += Wa[j * 16 + i] * ef[i];
    hs = fmaxf(hs, 0.f);
    #pragma unroll
    for (int o = 0; o < 8; o++) m[o] += Wb[j * 8 + o] * hs;
  }

  // ---- seq MLP (lane-per-edge): sd = sn[dst]-sn[src] ----
  float sd[64];
  {
    const unsigned short* sA = snb + (size_t)dst * 64;
    const unsigned short* sB = snb + (size_t)src * 64;
    #pragma unroll
    for (int i8 = 0; i8 < 64; i8 += 8) {
      uint4 ua = *(const uint4*)(sA + i8);
      uint4 ub = *(const uint4*)(sB + i8);
      unsigned au[4] = {ua.x, ua.y, ua.z, ua.w};
      unsigned bu[4] = {ub.x, ub.y, ub.z, ub.w};
      #pragma unroll
      for (int w = 0; w < 4; w++) {
        sd[i8 + 2*w]     = bf_lo(au[w]) - bf_lo(bu[w]);
        sd[i8 + 2*w + 1] = bf_hi(au[w]) - bf_hi(bu[w]);
      }
    }
  }
  float sb[8];
  #pragma unroll
  for (int o = 0; o < 8; o++) sb[o] = sbs2[o];
  for (int j = 0; j < 128; j++) {
    float acc = sbs1[j];
    #pragma unroll
    for (int i = 0; i < 64; i += 4) {
      float4 w4 = *(const float4*)(&sWs1[j * 64 + i]);   // broadcast
      acc += w4.x * sd[i] + w4.y * sd[i+1] + w4.z * sd[i+2] + w4.w * sd[i+3];
    }
    float g = gelu_exact(acc);
    float4 w2a = *(const float4*)(&sWs2T[j * 8]);
    float4 w2b = *(const float4*)(&sWs2T[j * 8 + 4]);
    sb[0] += w2a.x * g; sb[1] += w2a.y * g; sb[2] += w2a.z * g; sb[3] += w2a.w * g;
    sb[4] += w2b.x * g; sb[5] += w2b.y * g; sb[6] += w2b.z * g; sb[7] += w2b.w * g;
  }
  float tv[8];
  #pragma unroll
  for (int o = 0; o < 8; o++) tv[o] = tanhf(sb[o]);

  // ---- QK dots + exp + denominator atomics ----
  {
    const unsigned short* qrow = qb + (size_t)dst * 128;
    const unsigned short* krow = kb + (size_t)src * 128;
    #pragma unroll
    for (int h = 0; h < 8; h++) {
      const uint4* qp = (const uint4*)(qrow + h * 16);
      const uint4* kp = (const uint4*)(krow + h * 16);
      float dot = 0.f;
      #pragma unroll
      for (int u = 0; u < 2; u++) {
        uint4 qu = qp[u], ku = kp[u];
        unsigned qa[4] = {qu.x, qu.y, qu.z, qu.w};
        unsigned ka[4] = {ku.x, ku.y, ku.z, ku.w};
        #pragma unroll
        for (int w = 0; w < 4; w++)
          dot += bf_lo(qa[w]) * bf_lo(ka[w]) + bf_hi(qa[w]) * bf_hi(ka[w]);
      }
      float logit = dot * 0.25f + m[h] + 0.1f * tv[h];
      float ex = __expf(logit);
      sEx[wid * 576 + lane * 9 + h] = ex;
      atomic_add_f32(&den[(size_t)dst * 8 + h], ex);
    }
  }
  __syncthreads();

  // ---- message scatter (wave-per-edge, coalesced) ----
  {
    const int h = lane >> 3;          // head for channels 2*lane, 2*lane+1
    const int c0 = lane * 2;
    for (int el = 0; el < 64; el++) {
      int s2 = __shfl(src, el);
      int d2 = __shfl(dst, el);
      float ex = sEx[wid * 576 + el * 9 + h];
      unsigned vv = *(const unsigned*)(vb + (size_t)s2 * 128 + c0);
      float v0 = bf_lo(vv), v1 = bf_hi(vv);
      atomic_add_f32(&num[(size_t)d2 * 128 + c0],     v0 * ex);
      atomic_add_f32(&num[(size_t)d2 * 128 + c0 + 1], v1 * ex);
    }
  }
}

// ---------- kernel 3: out = gelu(num/(den+1e-12)) + x ----------
__global__ __launch_bounds__(256) void finalize_k(
    const float* __restrict__ x, const float* __restrict__ num,
    const float* __restrict__ den, float* __restrict__ out)
{
  int idx = blockIdx.x * 256 + threadIdx.x;     // over NN*32 float4 units
  int n = idx >> 5;
  int c4 = (idx & 31) * 4;
  int h = c4 >> 4;
  float dv = den[(size_t)n * 8 + h] + 1e-12f;
  float inv = 1.0f / dv;
  float4 nm = *(const float4*)(num + (size_t)n * 128 + c4);
  float4 xx = *(const float4*)(x + (size_t)n * 128 + c4);
  float4 o;
  o.x = gelu_exact(nm.x * inv) + xx.x;
  o.y = gelu_exact(nm.y * inv) + xx.y;
  o.z = gelu_exact(nm.z * inv) + xx.z;
  o.w = gelu_exact(nm.w * inv) + xx.w;
  *(float4*)(out + (size_t)n * 128 + c4) = o;
}

extern "C" void kernel_launch(void* const* d_in, const int* in_sizes, int n_in,
                              void* d_out, int out_size, void* d_ws, size_t ws_size,
                              hipStream_t stream)
{
  const float* x    = (const float*)d_in[0];
  const int*   ei   = (const int*)d_in[1];
  const float* ea   = (const float*)d_in[2];
  const float* seq  = (const float*)d_in[3];
  const float* ln_g = (const float*)d_in[4];
  const float* ln_b = (const float*)d_in[5];
  const float* Wq   = (const float*)d_in[6];
  const float* bq   = (const float*)d_in[7];
  const float* Wk   = (const float*)d_in[8];
  const float* bk   = (const float*)d_in[9];
  const float* Wv   = (const float*)d_in[10];
  const float* bv   = (const float*)d_in[11];
  const float* We0a = (const float*)d_in[12];
  const float* be0a = (const float*)d_in[13];
  const float* We0b = (const float*)d_in[14];
  const float* be0b = (const float*)d_in[15];
  const float* We1a = (const float*)d_in[16];
  const float* be1a = (const float*)d_in[17];
  const float* We1b = (const float*)d_in[18];
  const float* be1b = (const float*)d_in[19];
  const float* Ws1  = (const float*)d_in[20];
  const float* bs1  = (const float*)d_in[21];
  const float* Ws2  = (const float*)d_in[22];
  const float* bs2  = (const float*)d_in[23];
  float* out = (float*)d_out;

  // workspace layout (72 MB total)
  unsigned short* qb  = (unsigned short*)d_ws;
  unsigned short* kb  = qb + (size_t)NN * 128;
  unsigned short* vb  = kb + (size_t)NN * 128;
  unsigned short* snb = vb + (size_t)NN * 128;
  float* num = (float*)(snb + (size_t)NN * 64);
  float* den = num + (size_t)NN * 128;

  hipMemsetAsync(num, 0, (size_t)(NN * 128 + NN * 8) * sizeof(float), stream);

  node_pre<<<(NN + NB - 1) / NB, 384, 0, stream>>>(
      x, seq, ln_g, ln_b, Wq, bq, Wk, bk, Wv, bv, qb, kb, vb, snb);

  edge_k<<<EE / 256, 256, 0, stream>>>(
      ei, ea, qb, kb, vb, snb,
      We0a, be0a, We0b, be0b, We1a, be1a, We1b, be1b,
      Ws1, bs1, Ws2, bs2, num, den);

  finalize_k<<<(NN * 32) / 256, 256, 0, stream>>>(x, num, den, out);
}